// Round 3
// baseline (215.026 us; speedup 1.0000x reference)
//
#include <hip/hip_runtime.h>
#include <hip/hip_cooperative_groups.h>
#include <math.h>

namespace cg = cooperative_groups;

// Problem constants (from setup_inputs)
constexpr int B_ = 32, A_ = 3, S_ = 52, NC_ = 80;
constexpr int C_ = 5 + NC_;              // 85 channels in predictions
constexpr int N_ = B_ * A_ * S_ * S_;    // 259584 cells
constexpr int PAIRS = N_ / 2;            // 129792 cell-pairs
constexpr int BT = 256;                  // threads per block
constexpr int NB = PAIRS / BT;           // 507 blocks, exact fit (507*256 == PAIRS)
#define EPSF 1e-6f

// 4-value block reduction: wave shuffle (64 lanes) then LDS across 4 waves.
__device__ __forceinline__ void block_reduce4(float& a, float& b, float& c, float& d,
                                              float* out4 /* valid on tid 0 */) {
    #pragma unroll
    for (int off = 32; off > 0; off >>= 1) {
        a += __shfl_down(a, off, 64);
        b += __shfl_down(b, off, 64);
        c += __shfl_down(c, off, 64);
        d += __shfl_down(d, off, 64);
    }
    __shared__ float sm[BT / 64][4];
    const int lane = threadIdx.x & 63;
    const int wave = threadIdx.x >> 6;
    if (lane == 0) { sm[wave][0] = a; sm[wave][1] = b; sm[wave][2] = c; sm[wave][3] = d; }
    __syncthreads();
    if (threadIdx.x == 0) {
        float ra = 0.f, rb = 0.f, rc = 0.f, rd = 0.f;
        #pragma unroll
        for (int w = 0; w < BT / 64; ++w) {
            ra += sm[w][0]; rb += sm[w][1]; rc += sm[w][2]; rd += sm[w][3];
        }
        out4[0] = ra; out4[1] = rb; out4[2] = rc; out4[3] = rd;
    }
}

// Per-cell loss contribution. t0 is exactly 0.0 or 1.0.
__device__ __forceinline__ void cell_loss(
    int n, float t0, float t1, float t2, float t3, float t4, float logit,
    float a0w, float a0h, float a1w, float a1h, float a2w, float a2h,
    float& s_no, float& c_no, float& s_ob, float& c_ob)
{
    if (t0 == 0.f) {
        // BCE(logit, target=0) = max(l,0) + log1p(exp(-|l|))
        s_no += fmaxf(logit, 0.f) + log1pf(expf(-fabsf(logit)));
        c_no += 1.f;
    } else {
        const int j = n % S_;             // dim-3 index
        const int i = (n / S_) % S_;      // dim-2 index
        const int a = (n / (S_ * S_)) % A_;
        const float aw = (a == 0) ? a0w : (a == 1) ? a1w : a2w;
        const float ah = (a == 0) ? a0h : (a == 1) ? a1h : a2h;

        // decoded box (cx,cy,w,h)
        const float bx = 1.f / (1.f + expf(-t1)) + (float)i;
        const float by = 1.f / (1.f + expf(-t2)) + (float)j;
        const float bw = expf(t3) * aw;
        const float bh = expf(t4) * ah;

        // box1 = decoded, box2 = raw targets (faithful to reference)
        const float x1a = bx - bw * 0.5f, x2a = bx + bw * 0.5f;
        const float y1a = by - bh * 0.5f, y2a = by + bh * 0.5f;
        const float x1b = t1 - t3 * 0.5f, x2b = t1 + t3 * 0.5f;
        const float y1b = t2 - t4 * 0.5f, y2b = t2 + t4 * 0.5f;

        const float iw = fmaxf(fminf(x2a, x2b) - fmaxf(x1a, x1b), 0.f);
        const float ih = fmaxf(fminf(y2a, y2b) - fmaxf(y1a, y1b), 0.f);
        const float inter = iw * ih;
        const float uni = (x2a - x1a) * (y2a - y1a)
                        + (x2b - x1b) * (y2b - y1b) - inter;
        const float iou = inter / (uni + EPSF);

        // BCE(input=iou, target=logit)
        s_ob += fmaxf(iou, 0.f) - iou * logit + log1pf(expf(-fabsf(iou)));
        c_ob += 1.f;
    }
}

// Fused: per-pair partials -> grid sync -> block 0 final reduce.
__global__ __launch_bounds__(BT) void yolo_fused(
    const float* __restrict__ pred, const float* __restrict__ tgt,
    const float* __restrict__ anch, float* __restrict__ partials,
    float* __restrict__ out)
{
    const float a0w = anch[0], a0h = anch[1];
    const float a1w = anch[2], a1h = anch[3];
    const float a2w = anch[4], a2h = anch[5];

    const int p = blockIdx.x * BT + threadIdx.x;   // pair id, exact fit
    const int n0 = 2 * p;

    // targets for the pair: 12 consecutive floats, 48B-aligned (n0 even)
    const float4* tq = (const float4*)tgt + (size_t)3 * p;
    const float4 q0 = tq[0];
    const float4 q1 = tq[1];
    const float4 q2 = tq[2];

    const float l0 = pred[(size_t)n0 * C_];        // predictions[...,0]
    const float l1 = pred[(size_t)(n0 + 1) * C_];

    float s_no = 0.f, c_no = 0.f, s_ob = 0.f, c_ob = 0.f;

    // cell 0: t = {q0.x, q0.y, q0.z, q0.w, q1.x}
    cell_loss(n0,     q0.x, q0.y, q0.z, q0.w, q1.x, l0,
              a0w, a0h, a1w, a1h, a2w, a2h, s_no, c_no, s_ob, c_ob);
    // cell 1: t = {q1.z, q1.w, q2.x, q2.y, q2.z}
    cell_loss(n0 + 1, q1.z, q1.w, q2.x, q2.y, q2.z, l1,
              a0w, a0h, a1w, a1h, a2w, a2h, s_no, c_no, s_ob, c_ob);

    block_reduce4(s_no, c_no, s_ob, c_ob, &partials[(size_t)blockIdx.x * 4]);

    __threadfence();           // make partials visible device-wide (cross-XCD)
    cg::this_grid().sync();

    if (blockIdx.x == 0) {
        float f_no = 0.f, fc_no = 0.f, f_ob = 0.f, fc_ob = 0.f;
        for (int b = threadIdx.x; b < NB; b += BT) {
            f_no  += partials[b * 4 + 0];
            fc_no += partials[b * 4 + 1];
            f_ob  += partials[b * 4 + 2];
            fc_ob += partials[b * 4 + 3];
        }
        __shared__ float res[4];
        block_reduce4(f_no, fc_no, f_ob, fc_ob, res);
        if (threadIdx.x == 0) {
            const float no_obj_loss = res[0] / fmaxf(res[1], 1.f);
            const float obj_loss    = res[2] / fmaxf(res[3], 1.f);
            out[0] = 0.5f * no_obj_loss + obj_loss;
        }
    }
}

extern "C" void kernel_launch(void* const* d_in, const int* in_sizes, int n_in,
                              void* d_out, int out_size, void* d_ws, size_t ws_size,
                              hipStream_t stream) {
    const float* pred = (const float*)d_in[0];   // [32,3,52,52,85] f32
    const float* tgt  = (const float*)d_in[1];   // [32,3,52,52,6]  f32
    const float* anch = (const float*)d_in[2];   // [3,2]           f32
    float* out = (float*)d_out;                  // scalar f32
    float* partials = (float*)d_ws;              // NB*4 floats, all written each call

    void* args[] = { (void*)&pred, (void*)&tgt, (void*)&anch,
                     (void*)&partials, (void*)&out };
    hipLaunchCooperativeKernel((void*)yolo_fused, dim3(NB), dim3(BT),
                               args, 0, stream);
}

// Round 4
// 125.724 us; speedup vs baseline: 1.7103x; 1.7103x over previous
//
#include <hip/hip_runtime.h>
#include <math.h>

// Problem constants (from setup_inputs)
constexpr int B_ = 32, A_ = 3, S_ = 52, NC_ = 80;
constexpr int C_ = 5 + NC_;              // 85 channels in predictions
constexpr int N_ = B_ * A_ * S_ * S_;    // 259584 cells
constexpr int PAIRS = N_ / 2;            // 129792 cell-pairs
constexpr int BT = 256;                  // threads per block
constexpr int NB = PAIRS / BT;           // 507 blocks, exact fit (507*256 == PAIRS)
#define EPSF 1e-6f

// NOTE (R2 post-mortem): do NOT fuse these two kernels with
// hipLaunchCooperativeKernel + grid.sync() — measured 87 us for the fused
// kernel vs ~6-8 us for the two plain dispatches. Cross-XCD grid sync on
// MI355X costs ~80 us; a graph-replayed dispatch costs ~2 us.

// 4-value block reduction: wave shuffle (64 lanes) then LDS across 4 waves.
__device__ __forceinline__ void block_reduce4(float& a, float& b, float& c, float& d,
                                              float* out4 /* valid on tid 0 */) {
    #pragma unroll
    for (int off = 32; off > 0; off >>= 1) {
        a += __shfl_down(a, off, 64);
        b += __shfl_down(b, off, 64);
        c += __shfl_down(c, off, 64);
        d += __shfl_down(d, off, 64);
    }
    __shared__ float sm[BT / 64][4];
    const int lane = threadIdx.x & 63;
    const int wave = threadIdx.x >> 6;
    if (lane == 0) { sm[wave][0] = a; sm[wave][1] = b; sm[wave][2] = c; sm[wave][3] = d; }
    __syncthreads();
    if (threadIdx.x == 0) {
        float ra = 0.f, rb = 0.f, rc = 0.f, rd = 0.f;
        #pragma unroll
        for (int w = 0; w < BT / 64; ++w) {
            ra += sm[w][0]; rb += sm[w][1]; rc += sm[w][2]; rd += sm[w][3];
        }
        out4[0] = ra; out4[1] = rb; out4[2] = rc; out4[3] = rd;
    }
}

// Per-cell loss contribution. t0 is exactly 0.0 or 1.0.
__device__ __forceinline__ void cell_loss(
    int n, float t0, float t1, float t2, float t3, float t4, float logit,
    float a0w, float a0h, float a1w, float a1h, float a2w, float a2h,
    float& s_no, float& c_no, float& s_ob, float& c_ob)
{
    if (t0 == 0.f) {
        // BCE(logit, target=0) = max(l,0) + log1p(exp(-|l|))
        s_no += fmaxf(logit, 0.f) + log1pf(expf(-fabsf(logit)));
        c_no += 1.f;
    } else {
        const int j = n % S_;             // dim-3 index
        const int i = (n / S_) % S_;      // dim-2 index
        const int a = (n / (S_ * S_)) % A_;
        const float aw = (a == 0) ? a0w : (a == 1) ? a1w : a2w;
        const float ah = (a == 0) ? a0h : (a == 1) ? a1h : a2h;

        // decoded box (cx,cy,w,h)
        const float bx = 1.f / (1.f + expf(-t1)) + (float)i;
        const float by = 1.f / (1.f + expf(-t2)) + (float)j;
        const float bw = expf(t3) * aw;
        const float bh = expf(t4) * ah;

        // box1 = decoded, box2 = raw targets (faithful to reference)
        const float x1a = bx - bw * 0.5f, x2a = bx + bw * 0.5f;
        const float y1a = by - bh * 0.5f, y2a = by + bh * 0.5f;
        const float x1b = t1 - t3 * 0.5f, x2b = t1 + t3 * 0.5f;
        const float y1b = t2 - t4 * 0.5f, y2b = t2 + t4 * 0.5f;

        const float iw = fmaxf(fminf(x2a, x2b) - fmaxf(x1a, x1b), 0.f);
        const float ih = fmaxf(fminf(y2a, y2b) - fmaxf(y1a, y1b), 0.f);
        const float inter = iw * ih;
        const float uni = (x2a - x1a) * (y2a - y1a)
                        + (x2b - x1b) * (y2b - y1b) - inter;
        const float iou = inter / (uni + EPSF);

        // BCE(input=iou, target=logit)
        s_ob += fmaxf(iou, 0.f) - iou * logit + log1pf(expf(-fabsf(iou)));
        c_ob += 1.f;
    }
}

// Pass 1: each thread handles one pair of adjacent cells via 3 float4 loads.
__global__ __launch_bounds__(BT) void yolo_partial(
    const float* __restrict__ pred, const float* __restrict__ tgt,
    const float* __restrict__ anch, float* __restrict__ partials)
{
    const float a0w = anch[0], a0h = anch[1];
    const float a1w = anch[2], a1h = anch[3];
    const float a2w = anch[4], a2h = anch[5];

    const int p = blockIdx.x * BT + threadIdx.x;   // pair id, exact fit
    const int n0 = 2 * p;

    // targets for the pair: 12 consecutive floats, 48B-aligned (n0 even)
    const float4* tq = (const float4*)tgt + (size_t)3 * p;
    const float4 q0 = tq[0];
    const float4 q1 = tq[1];
    const float4 q2 = tq[2];

    const float l0 = pred[(size_t)n0 * C_];        // predictions[...,0]
    const float l1 = pred[(size_t)(n0 + 1) * C_];

    float s_no = 0.f, c_no = 0.f, s_ob = 0.f, c_ob = 0.f;

    // cell 0: t = {q0.x, q0.y, q0.z, q0.w, q1.x}, (q1.y unused class slot)
    cell_loss(n0,     q0.x, q0.y, q0.z, q0.w, q1.x, l0,
              a0w, a0h, a1w, a1h, a2w, a2h, s_no, c_no, s_ob, c_ob);
    // cell 1: t = {q1.z, q1.w, q2.x, q2.y, q2.z}
    cell_loss(n0 + 1, q1.z, q1.w, q2.x, q2.y, q2.z, l1,
              a0w, a0h, a1w, a1h, a2w, a2h, s_no, c_no, s_ob, c_ob);

    block_reduce4(s_no, c_no, s_ob, c_ob, &partials[(size_t)blockIdx.x * 4]);
}

// Pass 2: reduce NB partials, compute final scalar.
__global__ __launch_bounds__(BT) void yolo_final(
    const float* __restrict__ partials, float* __restrict__ out)
{
    float s_no = 0.f, c_no = 0.f, s_ob = 0.f, c_ob = 0.f;
    for (int b = threadIdx.x; b < NB; b += BT) {
        s_no += partials[b * 4 + 0];
        c_no += partials[b * 4 + 1];
        s_ob += partials[b * 4 + 2];
        c_ob += partials[b * 4 + 3];
    }
    __shared__ float res[4];
    block_reduce4(s_no, c_no, s_ob, c_ob, res);
    if (threadIdx.x == 0) {
        const float no_obj_loss = res[0] / fmaxf(res[1], 1.f);
        const float obj_loss    = res[2] / fmaxf(res[3], 1.f);
        out[0] = 0.5f * no_obj_loss + obj_loss;
    }
}

extern "C" void kernel_launch(void* const* d_in, const int* in_sizes, int n_in,
                              void* d_out, int out_size, void* d_ws, size_t ws_size,
                              hipStream_t stream) {
    const float* pred = (const float*)d_in[0];   // [32,3,52,52,85] f32
    const float* tgt  = (const float*)d_in[1];   // [32,3,52,52,6]  f32
    const float* anch = (const float*)d_in[2];   // [3,2]           f32
    float* out = (float*)d_out;                  // scalar f32
    float* partials = (float*)d_ws;              // NB*4 floats, all written each call

    yolo_partial<<<NB, BT, 0, stream>>>(pred, tgt, anch, partials);
    yolo_final<<<1, BT, 0, stream>>>(partials, out);
}